// Round 1
// baseline (270.068 us; speedup 1.0000x reference)
//
#include <hip/hip_runtime.h>
#include <hip/hip_bf16.h>
#include <stdint.h>

// FP8QDQLinear: out[m,o] = sum_i qdq_e4m3(in[m,i]/2)*2 * (w[o,i]*2) + bias[o]
//             = 4 * (q_in @ q_w^T) + bias,  q_* are exact e4m3 values.
// Strategy: quantize input+weight to fp8 in d_ws, then fp8 MFMA GEMM (m97/m145
// 128^2-tile structure), epilogue fuses *4 and +bias.

typedef __attribute__((ext_vector_type(4))) float f32x4;
typedef __attribute__((ext_vector_type(2))) int i32x2;

#define FP8_MAX 448.0f

// ---------------- quantization pass: f32 -> e4m3fn bytes ----------------
// Each thread: 8 floats -> 8 fp8 bytes. mul = 1/scale (0.5 for input, 1.0 for weight).
__global__ void quant_fp8_kernel(const float* __restrict__ x,
                                 uint32_t* __restrict__ q,
                                 float mul, int n8) {
    int i = blockIdx.x * blockDim.x + threadIdx.x;
    if (i >= n8) return;
    const float4* xv = (const float4*)x;
    float4 v0 = xv[2 * i];
    float4 v1 = xv[2 * i + 1];
    float a[8] = {v0.x, v0.y, v0.z, v0.w, v1.x, v1.y, v1.z, v1.w};
#pragma unroll
    for (int j = 0; j < 8; ++j) {
        float t = a[j] * mul;
        t = fminf(fmaxf(t, -FP8_MAX), FP8_MAX);
        a[j] = t;
    }
    int lo = 0, hi = 0;
    lo = __builtin_amdgcn_cvt_pk_fp8_f32(a[0], a[1], lo, false); // bytes 0,1
    lo = __builtin_amdgcn_cvt_pk_fp8_f32(a[2], a[3], lo, true);  // bytes 2,3
    hi = __builtin_amdgcn_cvt_pk_fp8_f32(a[4], a[5], hi, false);
    hi = __builtin_amdgcn_cvt_pk_fp8_f32(a[6], a[7], hi, true);
    i32x2 out;
    out.x = lo;
    out.y = hi;
    ((i32x2*)q)[i] = out;
}

// ---------------- fp8 GEMM: C = 4*(A_q @ W_q^T) + bias ----------------
// A_q [M][K] fp8 row-major, W_q [N][K] fp8 row-major (both K-major => symmetric
// fragment reads). 128x128 tile, BK=64 bytes, 256 threads = 4 waves (2x2),
// each wave owns a 64x64 output sub-tile = 4x4 fragments of 16x16.
#define TILE 128
#define BK 64

__device__ static inline void gload_lds16(const void* g, void* l) {
    __builtin_amdgcn_global_load_lds(
        (const __attribute__((address_space(1))) void*)g,
        (__attribute__((address_space(3))) void*)l, 16, 0, 0);
}

__global__ void fp8_gemm_bias_kernel(const uint8_t* __restrict__ Aq,
                                     const uint8_t* __restrict__ Wq,
                                     const float* __restrict__ bias,
                                     float* __restrict__ C,
                                     int M, int N, int K) {
    __shared__ __align__(16) uint8_t sA[TILE * BK];
    __shared__ __align__(16) uint8_t sB[TILE * BK];

    const int t = threadIdx.x;
    const int lane = t & 63;
    const int w = t >> 6;       // wave 0..3
    const int wr = w >> 1;      // wave row 0..1
    const int wc = w & 1;       // wave col 0..1
    const int lr = lane & 15;   // fragment row/col within 16
    const int lk = lane >> 4;   // k-group 0..3

    const int bm = blockIdx.y;
    const int bn = blockIdx.x;

    const uint8_t* Abase = Aq + (size_t)(bm * TILE) * K;
    const uint8_t* Bbase = Wq + (size_t)(bn * TILE) * K;

    // staging geometry: 256 threads x 16B = 4096B per call; tile = 8192B -> 2 calls
    const int srow = t >> 2;         // row within 64-row half, 4 threads/row
    const int scol = (t & 3) * 16;   // byte col within BK

    f32x4 acc[4][4];
#pragma unroll
    for (int m = 0; m < 4; ++m)
#pragma unroll
        for (int n = 0; n < 4; ++n)
            acc[m][n] = (f32x4){0.f, 0.f, 0.f, 0.f};

    for (int kt = 0; kt < K; kt += BK) {
#pragma unroll
        for (int c = 0; c < 2; ++c) {
            const uint8_t* ga = Abase + (size_t)(c * 64 + srow) * K + kt + scol;
            gload_lds16(ga, sA + c * 4096 + t * 16);
            const uint8_t* gb = Bbase + (size_t)(c * 64 + srow) * K + kt + scol;
            gload_lds16(gb, sB + c * 4096 + t * 16);
        }
        __syncthreads();  // compiler drains vmcnt(0) before barrier

#pragma unroll
        for (int kk = 0; kk < 2; ++kk) {
            long a[4], b[4];
#pragma unroll
            for (int m = 0; m < 4; ++m)
                a[m] = *(const long*)(sA + (wr * 64 + m * 16 + lr) * BK + kk * 32 + lk * 8);
#pragma unroll
            for (int n = 0; n < 4; ++n)
                b[n] = *(const long*)(sB + (wc * 64 + n * 16 + lr) * BK + kk * 32 + lk * 8);
#pragma unroll
            for (int m = 0; m < 4; ++m)
#pragma unroll
                for (int n = 0; n < 4; ++n)
                    acc[m][n] = __builtin_amdgcn_mfma_f32_16x16x32_fp8_fp8(
                        a[m], b[n], acc[m][n], 0, 0, 0);
        }
        __syncthreads();  // protect LDS before next stage overwrites
    }

    // epilogue: C/D layout col=lane&15, row=(lane>>4)*4+j  (dtype-independent)
    const int crow0 = bm * TILE + wr * 64 + lk * 4;
    const int ccol0 = bn * TILE + wc * 64 + lr;
#pragma unroll
    for (int n = 0; n < 4; ++n) {
        const int col = ccol0 + n * 16;
        const float bv = bias[col];
#pragma unroll
        for (int m = 0; m < 4; ++m) {
            const int row = crow0 + m * 16;
#pragma unroll
            for (int j = 0; j < 4; ++j) {
                C[(size_t)(row + j) * N + col] = acc[m][n][j] * 4.0f + bv;
            }
        }
    }
}

extern "C" void kernel_launch(void* const* d_in, const int* in_sizes, int n_in,
                              void* d_out, int out_size, void* d_ws, size_t ws_size,
                              hipStream_t stream) {
    const int M = 4096, N = 4096, K = 4096;
    const float* input  = (const float*)d_in[0];   // [M][K] f32
    const float* weight = (const float*)d_in[1];   // [N][K] f32 (e4m3-grid values)
    const float* bias   = (const float*)d_in[2];   // [N] f32
    float* out = (float*)d_out;                    // [M][N] f32

    uint8_t* Aq = (uint8_t*)d_ws;                        // 16 MiB
    uint8_t* Wq = (uint8_t*)d_ws + (size_t)M * K;        // 16 MiB

    // quantize input (x * 0.5, clamp, RNE->e4m3) and weight (exact cast)
    {
        int n8 = (M * K) / 8;
        int blocks = (n8 + 255) / 256;
        quant_fp8_kernel<<<blocks, 256, 0, stream>>>(input, (uint32_t*)Aq, 0.5f, n8);
        quant_fp8_kernel<<<blocks, 256, 0, stream>>>(weight, (uint32_t*)Wq, 1.0f, n8);
    }

    dim3 grid(N / TILE, M / TILE);
    fp8_gemm_bias_kernel<<<grid, 256, 0, stream>>>(Aq, Wq, bias, out, M, N, K);
}

// Round 2
// 181.665 us; speedup vs baseline: 1.4866x; 1.4866x over previous
//
#include <hip/hip_runtime.h>
#include <hip/hip_bf16.h>
#include <stdint.h>

// FP8QDQLinear: out[m,o] = 4 * (q_in @ q_w^T) + bias, q_* exact e4m3 values.
// R2: fix 8-way LDS bank conflict. LDS tile stored as column-major 16B chunks
// (slot = col16*128 + row); global_load_lds dest stays linear, the permutation
// is folded into the per-lane GLOBAL source address (guide rule #21).
// Fragment ds_read_b64 bank = (lr&7)*4 + (lk&1)*2 -> 4 dwords/bank (floor).

typedef __attribute__((ext_vector_type(4))) float f32x4;
typedef __attribute__((ext_vector_type(2))) int i32x2;

#define FP8_MAX 448.0f

// ---------------- quantization pass: f32 -> e4m3fn bytes ----------------
__global__ void quant_fp8_kernel(const float* __restrict__ x,
                                 uint32_t* __restrict__ q,
                                 float mul, int n8) {
    int i = blockIdx.x * blockDim.x + threadIdx.x;
    if (i >= n8) return;
    const float4* xv = (const float4*)x;
    float4 v0 = xv[2 * i];
    float4 v1 = xv[2 * i + 1];
    float a[8] = {v0.x, v0.y, v0.z, v0.w, v1.x, v1.y, v1.z, v1.w};
#pragma unroll
    for (int j = 0; j < 8; ++j) {
        float t = a[j] * mul;
        t = fminf(fmaxf(t, -FP8_MAX), FP8_MAX);
        a[j] = t;
    }
    int lo = 0, hi = 0;
    lo = __builtin_amdgcn_cvt_pk_fp8_f32(a[0], a[1], lo, false);
    lo = __builtin_amdgcn_cvt_pk_fp8_f32(a[2], a[3], lo, true);
    hi = __builtin_amdgcn_cvt_pk_fp8_f32(a[4], a[5], hi, false);
    hi = __builtin_amdgcn_cvt_pk_fp8_f32(a[6], a[7], hi, true);
    i32x2 out;
    out.x = lo;
    out.y = hi;
    ((i32x2*)q)[i] = out;
}

// ---------------- fp8 GEMM: C = 4*(A_q @ W_q^T) + bias ----------------
// 128x128 tile, BK=64 bytes, 256 threads = 4 waves (2x2), each wave a 64x64
// output sub-tile = 4x4 fragments of 16x16x32 fp8 MFMA.
#define TILE 128
#define BK 64

__device__ static inline void gload_lds16(const void* g, void* l) {
    __builtin_amdgcn_global_load_lds(
        (const __attribute__((address_space(1))) void*)g,
        (__attribute__((address_space(3))) void*)l, 16, 0, 0);
}

__global__ void fp8_gemm_bias_kernel(const uint8_t* __restrict__ Aq,
                                     const uint8_t* __restrict__ Wq,
                                     const float* __restrict__ bias,
                                     float* __restrict__ C,
                                     int M, int N, int K) {
    // physical layout: 512 chunks of 16B; slot = col16*128 + row
    __shared__ __align__(16) uint8_t sA[TILE * BK];
    __shared__ __align__(16) uint8_t sB[TILE * BK];

    const int t = threadIdx.x;
    const int lane = t & 63;
    const int w = t >> 6;       // wave 0..3
    const int wr = w >> 1;      // wave row 0..1
    const int wc = w & 1;       // wave col 0..1
    const int lr = lane & 15;   // fragment row within 16
    const int lk = lane >> 4;   // k-group 0..3

    const int bm = blockIdx.y;
    const int bn = blockIdx.x;

    const uint8_t* Abase = Aq + (size_t)(bm * TILE) * K;
    const uint8_t* Bbase = Wq + (size_t)(bn * TILE) * K;

    // staging: chunk s = c*256 + t; row = s&127 (= t&127); col16 = c*2 + (t>>7)
    const int srow = t & 127;
    const int scol0 = (t >> 7) * 16;   // 0 or 16
    const uint8_t* gaA = Abase + (size_t)srow * K + scol0;
    const uint8_t* gaB = Bbase + (size_t)srow * K + scol0;

    // fragment read base: addr = ((kk*2 + (lane>>5))*128 + row)*16 + ((lane>>4)&1)*8
    //                   = base + kk*4096 + m*256
    const int aoff = (((lane >> 5) * 128) + wr * 64 + lr) * 16 + ((lk & 1) * 8);
    const int boff = (((lane >> 5) * 128) + wc * 64 + lr) * 16 + ((lk & 1) * 8);

    f32x4 acc[4][4];
#pragma unroll
    for (int m = 0; m < 4; ++m)
#pragma unroll
        for (int n = 0; n < 4; ++n)
            acc[m][n] = (f32x4){0.f, 0.f, 0.f, 0.f};

    for (int kt = 0; kt < K; kt += BK) {
        // c=0: chunks 0..255 (col16 0/1); c=1: chunks 256..511 (col16 2/3)
        gload_lds16(gaA + kt, sA + t * 16);
        gload_lds16(gaA + kt + 32, sA + 4096 + t * 16);
        gload_lds16(gaB + kt, sB + t * 16);
        gload_lds16(gaB + kt + 32, sB + 4096 + t * 16);
        __syncthreads();

#pragma unroll
        for (int kk = 0; kk < 2; ++kk) {
            long a[4], b[4];
#pragma unroll
            for (int m = 0; m < 4; ++m)
                a[m] = *(const long*)(sA + aoff + kk * 4096 + m * 256);
#pragma unroll
            for (int n = 0; n < 4; ++n)
                b[n] = *(const long*)(sB + boff + kk * 4096 + n * 256);
#pragma unroll
            for (int m = 0; m < 4; ++m)
#pragma unroll
                for (int n = 0; n < 4; ++n)
                    acc[m][n] = __builtin_amdgcn_mfma_f32_16x16x32_fp8_fp8(
                        a[m], b[n], acc[m][n], 0, 0, 0);
        }
        __syncthreads();
    }

    // epilogue: C/D layout col=lane&15, row=(lane>>4)*4+j (dtype-independent)
    const int crow0 = bm * TILE + wr * 64 + lk * 4;
    const int ccol0 = bn * TILE + wc * 64 + lr;
#pragma unroll
    for (int n = 0; n < 4; ++n) {
        const int col = ccol0 + n * 16;
        const float bv = bias[col];
#pragma unroll
        for (int m = 0; m < 4; ++m) {
            const int row = crow0 + m * 16;
#pragma unroll
            for (int j = 0; j < 4; ++j) {
                C[(size_t)(row + j) * N + col] = acc[m][n][j] * 4.0f + bv;
            }
        }
    }
}

extern "C" void kernel_launch(void* const* d_in, const int* in_sizes, int n_in,
                              void* d_out, int out_size, void* d_ws, size_t ws_size,
                              hipStream_t stream) {
    const int M = 4096, N = 4096, K = 4096;
    const float* input  = (const float*)d_in[0];   // [M][K] f32
    const float* weight = (const float*)d_in[1];   // [N][K] f32 (e4m3-grid values)
    const float* bias   = (const float*)d_in[2];   // [N] f32
    float* out = (float*)d_out;                    // [M][N] f32

    uint8_t* Aq = (uint8_t*)d_ws;                        // 16 MiB
    uint8_t* Wq = (uint8_t*)d_ws + (size_t)M * K;        // 16 MiB

    {
        int n8 = (M * K) / 8;
        int blocks = (n8 + 255) / 256;
        quant_fp8_kernel<<<blocks, 256, 0, stream>>>(input, (uint32_t*)Aq, 0.5f, n8);
        quant_fp8_kernel<<<blocks, 256, 0, stream>>>(weight, (uint32_t*)Wq, 1.0f, n8);
    }

    dim3 grid(N / TILE, M / TILE);
    fp8_gemm_bias_kernel<<<grid, 256, 0, stream>>>(Aq, Wq, bias, out, M, N, K);
}

// Round 3
// 163.382 us; speedup vs baseline: 1.6530x; 1.1119x over previous
//
#include <hip/hip_runtime.h>
#include <hip/hip_bf16.h>
#include <stdint.h>

// FP8QDQLinear: out[m,o] = 4 * (q_in @ q_w^T) + bias, q_* exact e4m3 values.
// R3: MX-scaled fp8 MFMA (16x16x128 f8f6f4, unit E8M0 scales = exact math) at
// 2x the non-scaled fp8 rate (ladder m148: 1628 TF on this 128^2 structure).
// LDS: column-major 16B chunks (slot = col16*128 + row); global_load_lds dest
// linear, permutation folded into per-lane GLOBAL source (rule #21).

typedef __attribute__((ext_vector_type(4))) float f32x4;
typedef __attribute__((ext_vector_type(2))) int i32x2;
typedef __attribute__((ext_vector_type(4))) int i32x4;
typedef __attribute__((ext_vector_type(8))) int i32x8;

#define FP8_MAX 448.0f

// ---------------- quantization pass: f32 -> e4m3fn bytes ----------------
__global__ void quant_fp8_kernel(const float* __restrict__ x,
                                 uint32_t* __restrict__ q,
                                 float mul, int n8) {
    int i = blockIdx.x * blockDim.x + threadIdx.x;
    if (i >= n8) return;
    const float4* xv = (const float4*)x;
    float4 v0 = xv[2 * i];
    float4 v1 = xv[2 * i + 1];
    float a[8] = {v0.x, v0.y, v0.z, v0.w, v1.x, v1.y, v1.z, v1.w};
#pragma unroll
    for (int j = 0; j < 8; ++j) {
        float t = a[j] * mul;
        t = fminf(fmaxf(t, -FP8_MAX), FP8_MAX);
        a[j] = t;
    }
    int lo = 0, hi = 0;
    lo = __builtin_amdgcn_cvt_pk_fp8_f32(a[0], a[1], lo, false);
    lo = __builtin_amdgcn_cvt_pk_fp8_f32(a[2], a[3], lo, true);
    hi = __builtin_amdgcn_cvt_pk_fp8_f32(a[4], a[5], hi, false);
    hi = __builtin_amdgcn_cvt_pk_fp8_f32(a[6], a[7], hi, true);
    i32x2 out;
    out.x = lo;
    out.y = hi;
    ((i32x2*)q)[i] = out;
}

// ---------------- MX-fp8 GEMM: C = 4*(A_q @ W_q^T) + bias ----------------
// 128x128 tile, BK=128 bytes, 256 threads = 4 waves (2x2), each wave a 64x64
// output sub-tile = 4x4 fragments of 16x16x128 scaled MFMA (one per K-step).
#define TILE 128
#define BK 128
#define UNIT_SCALE 0x7F7F7F7F  // E8M0 127 = 2^0 in every byte

__device__ static inline void gload_lds16(const void* g, void* l) {
    __builtin_amdgcn_global_load_lds(
        (const __attribute__((address_space(1))) void*)g,
        (__attribute__((address_space(3))) void*)l, 16, 0, 0);
}

__global__ void fp8_gemm_bias_kernel(const uint8_t* __restrict__ Aq,
                                     const uint8_t* __restrict__ Wq,
                                     const float* __restrict__ bias,
                                     float* __restrict__ C,
                                     int M, int N, int K) {
    // physical layout: 1024 chunks of 16B; slot = col16*128 + row, col16 in [0,8)
    __shared__ __align__(16) uint8_t sA[TILE * BK];
    __shared__ __align__(16) uint8_t sB[TILE * BK];

    const int t = threadIdx.x;
    const int lane = t & 63;
    const int w = t >> 6;       // wave 0..3
    const int wr = w >> 1;      // wave row 0..1
    const int wc = w & 1;       // wave col 0..1
    const int lr = lane & 15;   // fragment row within 16
    const int lk = lane >> 4;   // k-group 0..3 (32 bytes each)

    const int bm = blockIdx.y;
    const int bn = blockIdx.x;

    const uint8_t* Abase = Aq + (size_t)(bm * TILE) * K;
    const uint8_t* Bbase = Wq + (size_t)(bn * TILE) * K;

    // staging: call c stages chunks s = c*256 + t; col16 = c*2 + (t>>7), row = t&127
    const int srow = t & 127;
    const int scol0 = (t >> 7) * 16;   // 0 or 16
    const uint8_t* gaA = Abase + (size_t)srow * K + scol0;
    const uint8_t* gaB = Bbase + (size_t)srow * K + scol0;

    // fragment: lane reads chunks col16 = lk*2, lk*2+1 at row wr*64 + m*16 + lr
    const int aoff = lk * 4096 + (wr * 64 + lr) * 16;
    const int boff = lk * 4096 + (wc * 64 + lr) * 16;

    f32x4 acc[4][4];
#pragma unroll
    for (int m = 0; m < 4; ++m)
#pragma unroll
        for (int n = 0; n < 4; ++n)
            acc[m][n] = (f32x4){0.f, 0.f, 0.f, 0.f};

    for (int kt = 0; kt < K; kt += BK) {
        gload_lds16(gaA + kt,      sA + t * 16);
        gload_lds16(gaA + kt + 32, sA + 4096  + t * 16);
        gload_lds16(gaA + kt + 64, sA + 8192  + t * 16);
        gload_lds16(gaA + kt + 96, sA + 12288 + t * 16);
        gload_lds16(gaB + kt,      sB + t * 16);
        gload_lds16(gaB + kt + 32, sB + 4096  + t * 16);
        gload_lds16(gaB + kt + 64, sB + 8192  + t * 16);
        gload_lds16(gaB + kt + 96, sB + 12288 + t * 16);
        __syncthreads();

        i32x8 a[4], b[4];
#pragma unroll
        for (int m = 0; m < 4; ++m) {
            i32x4 lo = *(const i32x4*)(sA + aoff + m * 256);
            i32x4 hi = *(const i32x4*)(sA + aoff + m * 256 + 2048);
            a[m] = (i32x8){lo[0], lo[1], lo[2], lo[3], hi[0], hi[1], hi[2], hi[3]};
        }
#pragma unroll
        for (int n = 0; n < 4; ++n) {
            i32x4 lo = *(const i32x4*)(sB + boff + n * 256);
            i32x4 hi = *(const i32x4*)(sB + boff + n * 256 + 2048);
            b[n] = (i32x8){lo[0], lo[1], lo[2], lo[3], hi[0], hi[1], hi[2], hi[3]};
        }
#pragma unroll
        for (int m = 0; m < 4; ++m)
#pragma unroll
            for (int n = 0; n < 4; ++n)
                acc[m][n] = __builtin_amdgcn_mfma_scale_f32_16x16x128_f8f6f4(
                    a[m], b[n], acc[m][n],
                    0 /*cbsz: A=fp8*/, 0 /*blgp: B=fp8*/,
                    0, UNIT_SCALE, 0, UNIT_SCALE);
        __syncthreads();
    }

    // epilogue: C/D layout col=lane&15, row=(lane>>4)*4+j (shape-determined)
    const int crow0 = bm * TILE + wr * 64 + lk * 4;
    const int ccol0 = bn * TILE + wc * 64 + lr;
#pragma unroll
    for (int n = 0; n < 4; ++n) {
        const int col = ccol0 + n * 16;
        const float bv = bias[col];
#pragma unroll
        for (int m = 0; m < 4; ++m) {
            const int row = crow0 + m * 16;
#pragma unroll
            for (int j = 0; j < 4; ++j) {
                C[(size_t)(row + j) * N + col] = acc[m][n][j] * 4.0f + bv;
            }
        }
    }
}

extern "C" void kernel_launch(void* const* d_in, const int* in_sizes, int n_in,
                              void* d_out, int out_size, void* d_ws, size_t ws_size,
                              hipStream_t stream) {
    const int M = 4096, N = 4096, K = 4096;
    const float* input  = (const float*)d_in[0];   // [M][K] f32
    const float* weight = (const float*)d_in[1];   // [N][K] f32 (e4m3-grid values)
    const float* bias   = (const float*)d_in[2];   // [N] f32
    float* out = (float*)d_out;                    // [M][N] f32

    uint8_t* Aq = (uint8_t*)d_ws;                        // 16 MiB
    uint8_t* Wq = (uint8_t*)d_ws + (size_t)M * K;        // 16 MiB

    {
        int n8 = (M * K) / 8;
        int blocks = (n8 + 255) / 256;
        quant_fp8_kernel<<<blocks, 256, 0, stream>>>(input, (uint32_t*)Aq, 0.5f, n8);
        quant_fp8_kernel<<<blocks, 256, 0, stream>>>(weight, (uint32_t*)Wq, 1.0f, n8);
    }

    dim3 grid(N / TILE, M / TILE);
    fp8_gemm_bias_kernel<<<grid, 256, 0, stream>>>(Aq, Wq, bias, out, M, N, K);
}